// Round 3
// baseline (238.336 us; speedup 1.0000x reference)
//
#include <hip/hip_runtime.h>

// AtomwiseReadout: out[m] = sum_{a in mol m} ( f[a,:] . w_e + z_bias[z[a]] )
// Molecules are contiguous runs of num_atoms[m] atoms (jnp.repeat semantics):
// exclusive prefix sum of num_atoms -> offsets, then one fused pass over f.
//
// R3 changes vs R2:
//  - single scan kernel: each block computes its own cross-chunk prefix by
//    summing ALL preceding counts (cnt is 400KB, L2-resident; ~1us aggregate).
//    2 dispatches total instead of 3.
//  - main kernel fast path for c==20 (the dominant count): compile-time
//    unrolled 2x5 float4 loads -> ~5 outstanding loads/wave instead of ~2,
//    while keeping register footprint <=64 VGPR (8 waves/SIMD).

#define FEAT 128          // f feature dim
#define SCAN_CHUNK 1024   // molecules per scan block
#define SCAN_THREADS 256

// ---------------- scan kernel: offsets in one dispatch ----------------
__global__ void k_offsets_fused(const int* __restrict__ cnt, int n,
                                int* __restrict__ offsets) {
    __shared__ int tsum[SCAN_THREADS];
    __shared__ int s_prefix;
    const int t = threadIdx.x;
    const int chunk_base = blockIdx.x * SCAN_CHUNK;

    // cross-chunk exclusive prefix: sum of all counts before this chunk.
    // cnt is ~400KB -> L2-resident; coalesced strided reads across threads.
    int p = 0;
    for (int j = t; j < chunk_base; j += SCAN_THREADS) p += cnt[j];
    tsum[t] = p;
    __syncthreads();
    for (int s = SCAN_THREADS / 2; s > 0; s >>= 1) {
        if (t < s) tsum[t] += tsum[t + s];
        __syncthreads();
    }
    if (t == 0) s_prefix = tsum[0];
    __syncthreads();
    const int chunk_prefix = s_prefix;
    __syncthreads();  // tsum reused below

    // per-chunk exclusive scan (4 molecules per thread)
    const int per_thread = SCAN_CHUNK / SCAN_THREADS;  // 4
    const int base_idx = chunk_base + t * per_thread;

    int v[per_thread];
    int s = 0;
#pragma unroll
    for (int j = 0; j < per_thread; ++j) {
        int idx = base_idx + j;
        v[j] = (idx < n) ? cnt[idx] : 0;
        s += v[j];
    }
    tsum[t] = s;
    __syncthreads();

    // Hillis-Steele inclusive scan over thread sums
    for (int off = 1; off < SCAN_THREADS; off <<= 1) {
        int val = (t >= off) ? tsum[t - off] : 0;
        __syncthreads();
        tsum[t] += val;
        __syncthreads();
    }
    int running = chunk_prefix + (tsum[t] - s);  // exclusive prefix
#pragma unroll
    for (int j = 0; j < per_thread; ++j) {
        int idx = base_idx + j;
        if (idx < n) offsets[idx] = running;
        running += v[j];
    }
}

// ---------------- main kernel: one wave per molecule -------------------
__global__ void __launch_bounds__(256)
k_readout(const float* __restrict__ f, const int* __restrict__ z,
          const int* __restrict__ cnt, const int* __restrict__ offsets,
          const float* __restrict__ w_e, const float* __restrict__ z_bias,
          float* __restrict__ out, int n_mol) {
    __shared__ float s_out[4];
    const int lane = threadIdx.x & 63;
    const int wave = threadIdx.x >> 6;
    const int m = blockIdx.x * 4 + wave;

    if (m < n_mol) {
        const int start = offsets[m];
        const int c = cnt[m];

        // Each half-wave (32 lanes x float4 = 512B) owns one atom row.
        const int half = lane >> 5;    // which row of the pair
        const int qlane = lane & 31;   // float4 slot within the row

        const float4 w = reinterpret_cast<const float4*>(w_e)[qlane];
        const float4* __restrict__ f4 = reinterpret_cast<const float4*>(f);

        float acc = 0.f;

        // per-element embedding bias (c <= 64 covered by one pass; loop for safety)
        for (int i = lane; i < c; i += 64) acc += z_bias[z[start + i]];

        if (c == 20) {
            // fast path: fully unrolled, loads batch-issued 5 at a time
            const float4* __restrict__ fr =
                f4 + (size_t)(start + half) * (FEAT / 4) + qlane;
#pragma unroll
            for (int h = 0; h < 2; ++h) {
                float4 v[5];
#pragma unroll
                for (int q = 0; q < 5; ++q)
                    v[q] = fr[(size_t)(h * 5 + q) * (2 * FEAT / 4)];
#pragma unroll
                for (int q = 0; q < 5; ++q) {
                    acc = fmaf(v[q].x, w.x, acc);
                    acc = fmaf(v[q].y, w.y, acc);
                    acc = fmaf(v[q].z, w.z, acc);
                    acc = fmaf(v[q].w, w.w, acc);
                }
            }
        } else {
            const int pairs = c >> 1;
            for (int p = 0; p < pairs; ++p) {
                const size_t row = (size_t)(start + 2 * p + half);
                float4 fv = f4[row * (FEAT / 4) + qlane];
                acc = fmaf(fv.x, w.x, acc);
                acc = fmaf(fv.y, w.y, acc);
                acc = fmaf(fv.z, w.z, acc);
                acc = fmaf(fv.w, w.w, acc);
            }
            if ((c & 1) && half == 0) {
                const size_t row = (size_t)(start + c - 1);
                float4 fv = f4[row * (FEAT / 4) + qlane];
                acc = fmaf(fv.x, w.x, acc);
                acc = fmaf(fv.y, w.y, acc);
                acc = fmaf(fv.z, w.z, acc);
                acc = fmaf(fv.w, w.w, acc);
            }
        }

        // 64-lane shuffle reduce
#pragma unroll
        for (int off = 32; off > 0; off >>= 1) acc += __shfl_down(acc, off);
        if (lane == 0) s_out[wave] = acc;
    }
    __syncthreads();

    if (threadIdx.x == 0) {
        const int base = blockIdx.x * 4;
        if (base + 3 < n_mol) {
            float4 v = make_float4(s_out[0], s_out[1], s_out[2], s_out[3]);
            *reinterpret_cast<float4*>(out + base) = v;
        } else {
            for (int i = 0; base + i < n_mol; ++i) out[base + i] = s_out[i];
        }
    }
}

extern "C" void kernel_launch(void* const* d_in, const int* in_sizes, int n_in,
                              void* d_out, int out_size, void* d_ws, size_t ws_size,
                              hipStream_t stream) {
    const int*   z      = (const int*)d_in[0];    // [N_ATOMS]
    const float* f      = (const float*)d_in[1];  // [N_ATOMS, 128]
    const int*   cnt    = (const int*)d_in[2];    // [N_MOL]
    const float* w_e    = (const float*)d_in[3];  // [128, 1]
    const float* z_bias = (const float*)d_in[4];  // [86, 1]
    float* out = (float*)d_out;                   // [N_MOL, 1]

    const int n_mol = in_sizes[2];

    int* offsets = (int*)d_ws;
    const int nb = (n_mol + SCAN_CHUNK - 1) / SCAN_CHUNK;

    k_offsets_fused<<<nb, SCAN_THREADS, 0, stream>>>(cnt, n_mol, offsets);

    const int waves_per_block = 4;  // 256 threads
    const int grid = (n_mol + waves_per_block - 1) / waves_per_block;
    k_readout<<<grid, 256, 0, stream>>>(f, z, cnt, offsets, w_e, z_bias,
                                        out, n_mol);
}

// Round 4
// 179.483 us; speedup vs baseline: 1.3279x; 1.3279x over previous
//
#include <hip/hip_runtime.h>

// AtomwiseReadout: out[m] = sum_{a in mol m} ( f[a,:] . w_e + z_bias[z[a]] )
// Molecules are contiguous runs of num_atoms[m] atoms (jnp.repeat semantics):
// exclusive prefix sum of num_atoms -> offsets, then one fused pass over f.
//
// R4: revert R3's fused scan (its last block serialized ~388 dependent
// L2 loads -> ~50us critical path; kernels in a stream serialize, so the
// main pass waited on the straggler). Back to R2's two-kernel scan where
// the cross-chunk prefix reads <=98 PRE-REDUCED block sums (1 load/thread).
// Keep the c==20 ILP fast path in the main kernel (5-deep load batches).

#define FEAT 128          // f feature dim
#define SCAN_CHUNK 1024   // molecules per scan block
#define SCAN_THREADS 256

// ---------------- scan kernel 1: per-chunk partial sums ----------------
__global__ void k_partial_sums(const int* __restrict__ cnt, int n,
                               int* __restrict__ block_sums) {
    __shared__ int sdata[SCAN_THREADS];
    const int chunk_base = blockIdx.x * SCAN_CHUNK;
    int local = 0;
    for (int i = threadIdx.x; i < SCAN_CHUNK; i += SCAN_THREADS) {
        int idx = chunk_base + i;
        if (idx < n) local += cnt[idx];
    }
    sdata[threadIdx.x] = local;
    __syncthreads();
    for (int s = SCAN_THREADS / 2; s > 0; s >>= 1) {
        if (threadIdx.x < s) sdata[threadIdx.x] += sdata[threadIdx.x + s];
        __syncthreads();
    }
    if (threadIdx.x == 0) block_sums[blockIdx.x] = sdata[0];
}

// ---------------- scan kernel 2: offsets (block-sum prefix) ------------
__global__ void k_offsets(const int* __restrict__ cnt, int n,
                          const int* __restrict__ block_sums,
                          int* __restrict__ offsets) {
    __shared__ int tsum[SCAN_THREADS];
    __shared__ int s_prefix;
    const int t = threadIdx.x;

    // cross-chunk exclusive prefix: <=98 pre-reduced values, 1 load/thread.
    int p = 0;
    for (int j = t; j < blockIdx.x; j += SCAN_THREADS) p += block_sums[j];
    tsum[t] = p;
    __syncthreads();
    for (int s = SCAN_THREADS / 2; s > 0; s >>= 1) {
        if (t < s) tsum[t] += tsum[t + s];
        __syncthreads();
    }
    if (t == 0) s_prefix = tsum[0];
    __syncthreads();
    const int chunk_prefix = s_prefix;
    __syncthreads();  // tsum reused below

    // per-chunk exclusive scan (4 molecules per thread)
    const int chunk_base = blockIdx.x * SCAN_CHUNK;
    const int per_thread = SCAN_CHUNK / SCAN_THREADS;  // 4
    const int base_idx = chunk_base + t * per_thread;

    int v[per_thread];
    int s = 0;
#pragma unroll
    for (int j = 0; j < per_thread; ++j) {
        int idx = base_idx + j;
        v[j] = (idx < n) ? cnt[idx] : 0;
        s += v[j];
    }
    tsum[t] = s;
    __syncthreads();

    // Hillis-Steele inclusive scan over thread sums
    for (int off = 1; off < SCAN_THREADS; off <<= 1) {
        int val = (t >= off) ? tsum[t - off] : 0;
        __syncthreads();
        tsum[t] += val;
        __syncthreads();
    }
    int running = chunk_prefix + (tsum[t] - s);  // exclusive prefix
#pragma unroll
    for (int j = 0; j < per_thread; ++j) {
        int idx = base_idx + j;
        if (idx < n) offsets[idx] = running;
        running += v[j];
    }
}

// ---------------- main kernel: one wave per molecule -------------------
__global__ void __launch_bounds__(256)
k_readout(const float* __restrict__ f, const int* __restrict__ z,
          const int* __restrict__ cnt, const int* __restrict__ offsets,
          const float* __restrict__ w_e, const float* __restrict__ z_bias,
          float* __restrict__ out, int n_mol) {
    __shared__ float s_out[4];
    const int lane = threadIdx.x & 63;
    const int wave = threadIdx.x >> 6;
    const int m = blockIdx.x * 4 + wave;

    if (m < n_mol) {
        const int start = offsets[m];
        const int c = cnt[m];

        // Each half-wave (32 lanes x float4 = 512B) owns one atom row.
        const int half = lane >> 5;    // which row of the pair
        const int qlane = lane & 31;   // float4 slot within the row

        const float4 w = reinterpret_cast<const float4*>(w_e)[qlane];
        const float4* __restrict__ f4 = reinterpret_cast<const float4*>(f);

        float acc = 0.f;

        // per-element embedding bias
        for (int i = lane; i < c; i += 64) acc += z_bias[z[start + i]];

        if (c == 20) {
            // fast path: fully unrolled, loads batch-issued 5 at a time
            const float4* __restrict__ fr =
                f4 + (size_t)(start + half) * (FEAT / 4) + qlane;
#pragma unroll
            for (int h = 0; h < 2; ++h) {
                float4 v[5];
#pragma unroll
                for (int q = 0; q < 5; ++q)
                    v[q] = fr[(size_t)(h * 5 + q) * (2 * FEAT / 4)];
#pragma unroll
                for (int q = 0; q < 5; ++q) {
                    acc = fmaf(v[q].x, w.x, acc);
                    acc = fmaf(v[q].y, w.y, acc);
                    acc = fmaf(v[q].z, w.z, acc);
                    acc = fmaf(v[q].w, w.w, acc);
                }
            }
        } else {
            const int pairs = c >> 1;
            for (int p = 0; p < pairs; ++p) {
                const size_t row = (size_t)(start + 2 * p + half);
                float4 fv = f4[row * (FEAT / 4) + qlane];
                acc = fmaf(fv.x, w.x, acc);
                acc = fmaf(fv.y, w.y, acc);
                acc = fmaf(fv.z, w.z, acc);
                acc = fmaf(fv.w, w.w, acc);
            }
            if ((c & 1) && half == 0) {
                const size_t row = (size_t)(start + c - 1);
                float4 fv = f4[row * (FEAT / 4) + qlane];
                acc = fmaf(fv.x, w.x, acc);
                acc = fmaf(fv.y, w.y, acc);
                acc = fmaf(fv.z, w.z, acc);
                acc = fmaf(fv.w, w.w, acc);
            }
        }

        // 64-lane shuffle reduce
#pragma unroll
        for (int off = 32; off > 0; off >>= 1) acc += __shfl_down(acc, off);
        if (lane == 0) s_out[wave] = acc;
    }
    __syncthreads();

    if (threadIdx.x == 0) {
        const int base = blockIdx.x * 4;
        if (base + 3 < n_mol) {
            float4 v = make_float4(s_out[0], s_out[1], s_out[2], s_out[3]);
            *reinterpret_cast<float4*>(out + base) = v;
        } else {
            for (int i = 0; base + i < n_mol; ++i) out[base + i] = s_out[i];
        }
    }
}

extern "C" void kernel_launch(void* const* d_in, const int* in_sizes, int n_in,
                              void* d_out, int out_size, void* d_ws, size_t ws_size,
                              hipStream_t stream) {
    const int*   z      = (const int*)d_in[0];    // [N_ATOMS]
    const float* f      = (const float*)d_in[1];  // [N_ATOMS, 128]
    const int*   cnt    = (const int*)d_in[2];    // [N_MOL]
    const float* w_e    = (const float*)d_in[3];  // [128, 1]
    const float* z_bias = (const float*)d_in[4];  // [86, 1]
    float* out = (float*)d_out;                   // [N_MOL, 1]

    const int n_mol = in_sizes[2];

    // workspace layout: offsets[n_mol] then block_sums[nb]
    int* offsets    = (int*)d_ws;
    const int nb    = (n_mol + SCAN_CHUNK - 1) / SCAN_CHUNK;
    int* block_sums = offsets + n_mol;

    k_partial_sums<<<nb, SCAN_THREADS, 0, stream>>>(cnt, n_mol, block_sums);
    k_offsets<<<nb, SCAN_THREADS, 0, stream>>>(cnt, n_mol, block_sums, offsets);

    const int waves_per_block = 4;  // 256 threads
    const int grid = (n_mol + waves_per_block - 1) / waves_per_block;
    k_readout<<<grid, 256, 0, stream>>>(f, z, cnt, offsets, w_e, z_bias,
                                        out, n_mol);
}